// Round 8
// baseline (245.433 us; speedup 1.0000x reference)
//
#include <hip/hip_runtime.h>
#include <hip/hip_bf16.h>

// EAConv: EM-routing neighbor aggregation + temporal blend.
// T=3, b=1, n=50000, d=64, m=16, K=4, dd=16.
// R8: attack the gather traffic (FETCH pegged at 236MB = 5x input across
// R3-R7; random 256B row-gathers miss the 4MB/XCD L2). Pre-pass normalizes
// x once and stores bf16 rows in d_ws (6.4MB/t): gathered bytes halve and
// the working set approaches L2 size. Agg keeps the R7 structure (one wave
// per (t,node); lane=(k,m); u unnormalized with rsqrt folded into logit;
// fused mov_dpp rowsums; clean 4-branch store).

constexpr int T  = 3;
constexpr int N  = 50000;
constexpr int D  = 64;
constexpr int M  = 16;
constexpr int DD = 16;
constexpr float EPS2 = 1e-24f;  // (1e-12)^2

template <int CTRL>
__device__ __forceinline__ float dpp_add(float v) {
    // mov_dpp (undef old) + add -> fuses to v_add_f32_dpp
    int rot = __builtin_amdgcn_mov_dpp(__float_as_int(v), CTRL, 0xF, 0xF, false);
    return v + __int_as_float(rot);
}
// sum over the 16 lanes of a row; result broadcast to every lane of the row
__device__ __forceinline__ float rowsum16(float v) {
    v = dpp_add<0x128>(v);  // row_ror:8
    v = dpp_add<0x124>(v);  // row_ror:4
    v = dpp_add<0x122>(v);  // row_ror:2
    v = dpp_add<0x121>(v);  // row_ror:1
    return v;
}

__device__ __forceinline__ unsigned short f2bf_rne(float f) {
    unsigned u = __float_as_uint(f);
    u = (u + 0x7fffu + ((u >> 16) & 1u)) >> 16;
    return (unsigned short)u;
}

// Pre-pass: per-factor L2 normalize, fp32 -> bf16. One thread per 4 dims
// (4 threads = one 16-dim factor; 2-step shuffle reduce).
__global__ __launch_bounds__(256) void norm_bf16(
    const float* __restrict__ x, unsigned short* __restrict__ xb)
{
    const int total = T * N * D / 4;
    int idx = blockIdx.x * blockDim.x + threadIdx.x;
    if (idx >= total) return;
    float4 v = ((const float4*)x)[idx];
    float s = v.x * v.x + v.y * v.y + v.z * v.z + v.w * v.w;
    s += __shfl_xor(s, 1, 64);
    s += __shfl_xor(s, 2, 64);
    const float r = __builtin_amdgcn_rsqf(fmaxf(s, EPS2));
    ushort4 o;
    o.x = f2bf_rne(v.x * r);
    o.y = f2bf_rne(v.y * r);
    o.z = f2bf_rne(v.z * r);
    o.w = f2bf_rne(v.w * r);
    ((ushort4*)xb)[idx] = o;
}

__global__ __launch_bounds__(256) void eaconv_agg_bf16(
    const float*          __restrict__ x_all,   // [T,N,D] raw (for xk)
    const unsigned short* __restrict__ xb,      // [T,N,D] normalized bf16
    const int*            __restrict__ nbr_all, // [T,N,M]
    float*                __restrict__ out)     // [T,N,D] <- U_t (pre-blend)
{
    const int wave = (blockIdx.x * blockDim.x + threadIdx.x) >> 6;
    const int lane = threadIdx.x & 63;
    if (wave >= T * N) return;
    const int t = wave / N;
    const int i = wave - t * N;
    const int m = lane & 15;
    const int k = lane >> 4;

    const float*          x  = x_all + (size_t)t * N * D;
    const unsigned short* xn = xb    + (size_t)t * N * D;

    int j = nbr_all[((size_t)t * N + i) * M + m];
    const bool valid = (unsigned)j < (unsigned)N;
    j = valid ? j : 0;
    const unsigned mask = valid ? 0xffffffffu : 0u;

    // own factor row fp32 (broadcast addr across the 16-lane row)
    const float4* xr = (const float4*)(x + (size_t)i * D + k * DD);
    float4 a0 = xr[0], a1 = xr[1], a2 = xr[2], a3 = xr[3];
    // neighbor factor row bf16 (scattered; 2 x 16B loads = 128B/row wave-wide)
    const uint4* zp = (const uint4*)(xn + (size_t)j * D + k * DD);
    uint4 c0 = zp[0], c1 = zp[1];

    float xk[DD] = {a0.x,a0.y,a0.z,a0.w, a1.x,a1.y,a1.z,a1.w,
                    a2.x,a2.y,a2.z,a2.w, a3.x,a3.y,a3.z,a3.w};

    unsigned cs[8] = {c0.x & mask, c0.y & mask, c0.z & mask, c0.w & mask,
                      c1.x & mask, c1.y & mask, c1.z & mask, c1.w & mask};
    float z[DD];
#pragma unroll
    for (int q = 0; q < 8; ++q) {
        z[2*q]   = __uint_as_float(cs[q] << 16);          // even dim (low u16)
        z[2*q+1] = __uint_as_float(cs[q] & 0xffff0000u);  // odd dim (high u16)
    }

    // xk: normalize in-lane (kept fp32 for accuracy of the additive term)
    float sx = xk[0]*xk[0];
#pragma unroll
    for (int p = 1; p < DD; ++p) sx = fmaf(xk[p], xk[p], sx);
    const float rx = __builtin_amdgcn_rsqf(fmaxf(sx, EPS2));
#pragma unroll
    for (int p = 0; p < DD; ++p) xk[p] *= rx;

    // ---- iter 0: u = sum_m z_m + 4*xk (direction; scale via logit) ----
    float u[DD];
#pragma unroll
    for (int p = 0; p < DD; ++p)
        u[p] = fmaf(xk[p], 4.0f, rowsum16(z[p]));
    float ns = u[0]*u[0];
#pragma unroll
    for (int p = 1; p < DD; ++p) ns = fmaf(u[p], u[p], ns);
    float inv = __builtin_amdgcn_rsqf(fmaxf(ns, EPS2));

    // ---- iters 1..2 ----
#pragma unroll
    for (int it = 1; it < 3; ++it) {
        float dot = z[0]*u[0];
#pragma unroll
        for (int p = 1; p < DD; ++p) dot = fmaf(z[p], u[p], dot);
        const float logit = dot * inv;         // zhat.uhat in [-1,1]
        const float e = __expf(logit);         // bounded: no max-sub
        float es = e + __shfl_xor(e, 16, 64);  // softmax denom over 4 factors
        es += __shfl_xor(es, 32, 64);
        const float wf = e * __builtin_amdgcn_rcpf(es);
#pragma unroll
        for (int p = 0; p < DD; ++p)
            u[p] = xk[p] + rowsum16(z[p] * wf);
        if (it < 2) {
            float na = u[0]*u[0];
#pragma unroll
            for (int p = 1; p < DD; ++p) na = fmaf(u[p], u[p], na);
            inv = __builtin_amdgcn_rsqf(fmaxf(na, EPS2));
        }
    }

    // store (clean 37.5 MB pattern): lanes m=0..3 write one float4 each
    float* o = out + ((size_t)t * N + i) * D + k * DD;
    if (m == 0) ((float4*)o)[0] = make_float4(u[0],  u[1],  u[2],  u[3]);
    if (m == 1) ((float4*)o)[1] = make_float4(u[4],  u[5],  u[6],  u[7]);
    if (m == 2) ((float4*)o)[2] = make_float4(u[8],  u[9],  u[10], u[11]);
    if (m == 3) ((float4*)o)[3] = make_float4(u[12], u[13], u[14], u[15]);
}

// fp32 fallback (R7) if d_ws is too small for the bf16 staging buffer
__global__ __launch_bounds__(256) void eaconv_agg_f32(
    const float* __restrict__ x_all, const int* __restrict__ nbr_all,
    float* __restrict__ out)
{
    const int wave = (blockIdx.x * blockDim.x + threadIdx.x) >> 6;
    const int lane = threadIdx.x & 63;
    if (wave >= T * N) return;
    const int t = wave / N;
    const int i = wave - t * N;
    const int m = lane & 15;
    const int k = lane >> 4;
    const float* x = x_all + (size_t)t * N * D;
    int j = nbr_all[((size_t)t * N + i) * M + m];
    const bool valid = (unsigned)j < (unsigned)N;
    j = valid ? j : 0;
    const float4* xr = (const float4*)(x + (size_t)i * D + k * DD);
    const float4* zr = (const float4*)(x + (size_t)j * D + k * DD);
    float4 a0 = xr[0], a1 = xr[1], a2 = xr[2], a3 = xr[3];
    float4 b0 = zr[0], b1 = zr[1], b2 = zr[2], b3 = zr[3];
    float xk[DD] = {a0.x,a0.y,a0.z,a0.w, a1.x,a1.y,a1.z,a1.w,
                    a2.x,a2.y,a2.z,a2.w, a3.x,a3.y,a3.z,a3.w};
    float z[DD]  = {b0.x,b0.y,b0.z,b0.w, b1.x,b1.y,b1.z,b1.w,
                    b2.x,b2.y,b2.z,b2.w, b3.x,b3.y,b3.z,b3.w};
    float sx = xk[0]*xk[0], sz = z[0]*z[0];
#pragma unroll
    for (int p = 1; p < DD; ++p) { sx = fmaf(xk[p], xk[p], sx);
                                   sz = fmaf(z[p],  z[p],  sz); }
    const float rx = __builtin_amdgcn_rsqf(fmaxf(sx, EPS2));
    float rz = __builtin_amdgcn_rsqf(fmaxf(sz, EPS2));
    if (!valid) rz = 0.f;
#pragma unroll
    for (int p = 0; p < DD; ++p) xk[p] *= rx;
    float u[DD];
#pragma unroll
    for (int p = 0; p < DD; ++p) u[p] = fmaf(xk[p], 4.0f, rowsum16(z[p] * rz));
    float ns = u[0]*u[0];
#pragma unroll
    for (int p = 1; p < DD; ++p) ns = fmaf(u[p], u[p], ns);
    float inv = __builtin_amdgcn_rsqf(fmaxf(ns, EPS2));
#pragma unroll
    for (int it = 1; it < 3; ++it) {
        float dot = z[0]*u[0];
#pragma unroll
        for (int p = 1; p < DD; ++p) dot = fmaf(z[p], u[p], dot);
        const float logit = dot * (rz * inv);
        const float e = __expf(logit);
        float es = e + __shfl_xor(e, 16, 64);
        es += __shfl_xor(es, 32, 64);
        const float wf = e * __builtin_amdgcn_rcpf(es) * rz;
#pragma unroll
        for (int p = 0; p < DD; ++p) u[p] = xk[p] + rowsum16(z[p] * wf);
        if (it < 2) {
            float na = u[0]*u[0];
#pragma unroll
            for (int p = 1; p < DD; ++p) na = fmaf(u[p], u[p], na);
            inv = __builtin_amdgcn_rsqf(fmaxf(na, EPS2));
        }
    }
    float* o = out + ((size_t)t * N + i) * D + k * DD;
    if (m == 0) ((float4*)o)[0] = make_float4(u[0],  u[1],  u[2],  u[3]);
    if (m == 1) ((float4*)o)[1] = make_float4(u[4],  u[5],  u[6],  u[7]);
    if (m == 2) ((float4*)o)[2] = make_float4(u[8],  u[9],  u[10], u[11]);
    if (m == 3) ((float4*)o)[3] = make_float4(u[12], u[13], u[14], u[15]);
}

// Temporal blend, closed form (sigmoid(0)=0.5, sigmoid(1)=0.7310585786):
//   e0 = u0;  e1 = 0.25*u0 + 0.5*u1;  e2 = (0.5*u0 + s1*e1)*0.25 + 0.5*u2
__global__ __launch_bounds__(256) void eaconv_combine(float* __restrict__ out) {
    const int nd4 = N * D / 4;
    int idx = blockIdx.x * blockDim.x + threadIdx.x;
    if (idx >= nd4) return;
    float4* o = (float4*)out;
    float4 u0 = o[idx];
    float4 u1 = o[nd4 + idx];
    float4 u2 = o[2 * nd4 + idx];
    const float s1 = 0.7310585786300049f;
    float4 e1, e2;
    e1.x = 0.25f * u0.x + 0.5f * u1.x;
    e1.y = 0.25f * u0.y + 0.5f * u1.y;
    e1.z = 0.25f * u0.z + 0.5f * u1.z;
    e1.w = 0.25f * u0.w + 0.5f * u1.w;
    e2.x = (0.5f * u0.x + s1 * e1.x) * 0.25f + 0.5f * u2.x;
    e2.y = (0.5f * u0.y + s1 * e1.y) * 0.25f + 0.5f * u2.y;
    e2.z = (0.5f * u0.z + s1 * e1.z) * 0.25f + 0.5f * u2.z;
    e2.w = (0.5f * u0.w + s1 * e1.w) * 0.25f + 0.5f * u2.w;
    o[nd4 + idx] = e1;
    o[2 * nd4 + idx] = e2;
}

extern "C" void kernel_launch(void* const* d_in, const int* in_sizes, int n_in,
                              void* d_out, int out_size, void* d_ws, size_t ws_size,
                              hipStream_t stream) {
    const float* x_all = (const float*)d_in[0];
    const int*   nbrs  = (const int*)d_in[1];
    float*       out   = (float*)d_out;

    const size_t xb_bytes = (size_t)T * N * D * sizeof(unsigned short);  // 19.2 MB
    const int total_threads = T * N * 64;  // one wave per (t,node)

    if (ws_size >= xb_bytes) {
        unsigned short* xb = (unsigned short*)d_ws;
        norm_bf16<<<(T * N * D / 4 + 255) / 256, 256, 0, stream>>>(x_all, xb);
        eaconv_agg_bf16<<<(total_threads + 255) / 256, 256, 0, stream>>>(
            x_all, xb, nbrs, out);
    } else {
        eaconv_agg_f32<<<(total_threads + 255) / 256, 256, 0, stream>>>(
            x_all, nbrs, out);
    }

    eaconv_combine<<<(N * D / 4 + 255) / 256, 256, 0, stream>>>(out);
}